// Round 16
// baseline (204.735 us; speedup 1.0000x reference)
//
#include <hip/hip_runtime.h>
#include <hip/hip_bf16.h>
#include <cstdint>
#include <cstddef>

#define BB 4
#define SEQ 2048
#define CD 768
#define NH 12
#define DH 64
#define MROWS (BB*SEQ)      // 8192
#define NQKV (3*CD)         // 2304

typedef float f32x4 __attribute__((ext_vector_type(4)));
typedef float f32x16 __attribute__((ext_vector_type(16)));
typedef short bf16x8 __attribute__((ext_vector_type(8)));

static __device__ __forceinline__ unsigned short f2bf(float f) {
  union { float f; unsigned int u; } cv; cv.f = f;
  unsigned int u = cv.u;
  unsigned int r = (u + 0x7FFFu + ((u >> 16) & 1u)) >> 16;
  return (unsigned short)r;
}

// raw v_exp_f32: our exponents are bounded (|x| <= ~23), no OCML fixups needed
static __device__ __forceinline__ float fexp2(float x) {
#if __has_builtin(__builtin_amdgcn_exp2f)
  return __builtin_amdgcn_exp2f(x);
#else
  float r; asm("v_exp_f32 %0, %1" : "=v"(r) : "v"(x)); return r;
#endif
}

#define GAS __attribute__((address_space(1)))
#define LAS __attribute__((address_space(3)))
static __device__ __forceinline__ void gl2lds16(const void* g, void* l) {
  __builtin_amdgcn_global_load_lds((const GAS void*)g, (LAS void*)l, 16, 0, 0);
}

#define MFMA(a, b, c) __builtin_amdgcn_mfma_f32_16x16x32_bf16((a), (b), (c), 0, 0, 0)
#define MFMA32(a, b, c) __builtin_amdgcn_mfma_f32_32x32x16_bf16((a), (b), (c), 0, 0, 0)
#define PACKBF(dst, x, y) asm("v_cvt_pk_bf16_f32 %0, %1, %2" : "=v"(dst) : "v"(x), "v"(y))
#define SWAP32(a, b) asm("v_permlane32_swap_b32 %0, %1" : "+v"(a), "+v"(b))

// 0.125 (1/sqrt(Dh)) * log2(e): folded into Q's gamma/beta so softmax uses exp2 directly.
// With LN'd q,k scores are bounded (|log2 score| <= 11.5) -> no max subtraction needed.
#define QSC 0.18033688011112042f

// ---------------- fp32 -> bf16 convert (x, qkv_w, proj_w in one launch) ----------------
#define CN1 (MROWS * CD / 4)
#define CN2 (CN1 + NQKV * CD / 4)
#define CN3 (CN2 + CD * CD / 4)
__global__ __launch_bounds__(256) void cvt_all(
    const float* __restrict__ x, const float* __restrict__ wq, const float* __restrict__ wp,
    unsigned short* __restrict__ Xb, unsigned short* __restrict__ Wq,
    unsigned short* __restrict__ Wp) {
  int i = blockIdx.x * 256 + threadIdx.x;
  if (i >= CN3) return;
  const float* src;
  unsigned short* dst;
  int k;
  if (i < CN1) { src = x; dst = Xb; k = i; }
  else if (i < CN2) { src = wq; dst = Wq; k = i - CN1; }
  else { src = wp; dst = Wp; k = i - CN2; }
  float4 v = reinterpret_cast<const float4*>(src)[k];
  unsigned int lo = (unsigned int)f2bf(v.x) | ((unsigned int)f2bf(v.y) << 16);
  unsigned int hi = (unsigned int)f2bf(v.z) | ((unsigned int)f2bf(v.w) << 16);
  reinterpret_cast<uint2*>(dst)[k] = make_uint2(lo, hi);
}

// ---------------- QKV GEMM: 128x128 tile, BK=64, 4 waves, swizzled LDS (R13) ----------------
__global__ __launch_bounds__(256) void qkv_gemm(
    const unsigned short* __restrict__ Xb, const unsigned short* __restrict__ Wb,
    const float* __restrict__ bias,
    const float* __restrict__ qg, const float* __restrict__ qbt,
    const float* __restrict__ kg, const float* __restrict__ kbt,
    unsigned short* __restrict__ Qo, unsigned short* __restrict__ Ko,
    unsigned short* __restrict__ Vt) {
  __shared__ unsigned short smem[4 * 128 * 64];   // 64KB: staging dbuf, then f32 C-buffer
#define ALS(buf) (&smem[(buf) * 8192])
#define BLS(buf) (&smem[16384 + (buf) * 8192])
  const int tid = threadIdx.x;
  const int wid = tid >> 6, lane = tid & 63;
  const int g = lane >> 4, cl = lane & 15;
  const int wr = (wid >> 1) * 64, wc = (wid & 1) * 64;

  const int wg = blockIdx.x;
  const int wgid = (wg & 7) * 144 + (wg >> 3);
  const int bm = wgid / 18, bn = wgid % 18;

  f32x4 acc[4][4] = {};

  const int srow = tid >> 3;                      // 0..31
  const int scol = ((tid & 7) ^ (srow & 7)) * 8;  // pre-swizzled source col
  const unsigned short* Abase = Xb + (size_t)(bm * 128 + srow) * CD + scol;
  const unsigned short* Bbase = Wb + (size_t)(bn * 128 + srow) * CD + scol;

#define QSTG(buf, kt)                                                         \
  do {                                                                        \
    gl2lds16(Abase + (size_t)0 * 32 * CD + (kt) * 64, ALS(buf) + 0 * 2048 + tid * 8); \
    gl2lds16(Abase + (size_t)1 * 32 * CD + (kt) * 64, ALS(buf) + 1 * 2048 + tid * 8); \
    gl2lds16(Abase + (size_t)2 * 32 * CD + (kt) * 64, ALS(buf) + 2 * 2048 + tid * 8); \
    gl2lds16(Abase + (size_t)3 * 32 * CD + (kt) * 64, ALS(buf) + 3 * 2048 + tid * 8); \
    gl2lds16(Bbase + (size_t)0 * 32 * CD + (kt) * 64, BLS(buf) + 0 * 2048 + tid * 8); \
    gl2lds16(Bbase + (size_t)1 * 32 * CD + (kt) * 64, BLS(buf) + 1 * 2048 + tid * 8); \
    gl2lds16(Bbase + (size_t)2 * 32 * CD + (kt) * 64, BLS(buf) + 2 * 2048 + tid * 8); \
    gl2lds16(Bbase + (size_t)3 * 32 * CD + (kt) * 64, BLS(buf) + 3 * 2048 + tid * 8); \
  } while (0)

  QSTG(0, 0);
  __syncthreads();
  const int NKT = CD / 64;  // 12
  for (int kt = 0; kt < NKT; ++kt) {
    const int cur = kt & 1;
    if (kt + 1 < NKT) QSTG(cur ^ 1, kt + 1);
    bf16x8 bfr[4][2];
#pragma unroll
    for (int j = 0; j < 4; ++j) {
      const int Bcol = wc + j * 16 + cl;
      const int sw = (Bcol & 7) << 3;
      bfr[j][0] = *(const bf16x8*)&BLS(cur)[Bcol * 64 + ((g * 8) ^ sw)];
      bfr[j][1] = *(const bf16x8*)&BLS(cur)[Bcol * 64 + ((32 + g * 8) ^ sw)];
    }
    __builtin_amdgcn_s_setprio(1);
#pragma unroll
    for (int i = 0; i < 4; ++i) {
      const int Arow = wr + i * 16 + cl;
      const int sw = (Arow & 7) << 3;
      bf16x8 a0 = *(const bf16x8*)&ALS(cur)[Arow * 64 + ((g * 8) ^ sw)];
      bf16x8 a1 = *(const bf16x8*)&ALS(cur)[Arow * 64 + ((32 + g * 8) ^ sw)];
#pragma unroll
      for (int j = 0; j < 4; ++j) {
        acc[i][j] = MFMA(a0, bfr[j][0], acc[i][j]);
        acc[i][j] = MFMA(a1, bfr[j][1], acc[i][j]);
      }
    }
    __builtin_amdgcn_s_setprio(0);
    __syncthreads();
  }
#undef QSTG

  // ---- LDS-bounce epilogue ----
  float* cb = (float*)smem;
#define CIDX(r, c) ((r) * 128 + (((((c) >> 2)) ^ ((r) & 31)) << 2) + ((c) & 3))
#pragma unroll
  for (int i = 0; i < 4; ++i)
#pragma unroll
    for (int j = 0; j < 4; ++j)
#pragma unroll
      for (int r = 0; r < 4; ++r)
        cb[CIDX(wr + i * 16 + g * 4 + r, wc + j * 16 + cl)] = acc[i][j][r];
  __syncthreads();

  const int t = bn / 6;
  const int h0 = (bn % 6) * 2;
  const int j0 = bn * 128;

  if (t == 2) {
    const int col = tid >> 1, nh = tid & 1;
    const int h = h0 + (col >> 6), d = col & 63;
    const float bia = bias[j0 + col];
    const int m0 = bm * 128;
    const int b = m0 >> 11;
    const int nn0 = (m0 & 2047) + nh * 64;
    unsigned short* dst = &Vt[((size_t)(b * NH + h) * DH + d) * SEQ + nn0];
#pragma unroll
    for (int k8 = 0; k8 < 8; ++k8) {
      union { unsigned short us[8]; uint4 v; } u;
#pragma unroll
      for (int e = 0; e < 8; ++e)
        u.us[e] = f2bf(cb[CIDX(nh * 64 + k8 * 8 + e, col)] + bia);
      *reinterpret_cast<uint4*>(&dst[k8 * 8]) = u.v;
    }
    return;
  }

  const int nl = tid >> 1, half = tid & 1;
  const int h = h0 + half;
  const int m = bm * 128 + nl;
  const int b = m >> 11, n = m & 2047;
  const float* gmp = (t == 0) ? qg : kg;
  const float* btp = (t == 0) ? qbt : kbt;
  const float sc = (t == 0) ? QSC : 1.0f;
  const float* bi = bias + j0 + half * 64;

  float v[64];
#pragma unroll
  for (int k4 = 0; k4 < 16; ++k4) {
    f32x4 q = *(const f32x4*)&cb[nl * 128 + ((((half * 16 + k4)) ^ (nl & 31)) << 2)];
    float4 b4 = reinterpret_cast<const float4*>(bi)[k4];
    v[k4 * 4 + 0] = q[0] + b4.x;
    v[k4 * 4 + 1] = q[1] + b4.y;
    v[k4 * 4 + 2] = q[2] + b4.z;
    v[k4 * 4 + 3] = q[3] + b4.w;
  }
  float s0 = 0, s1 = 0, s2 = 0, s3 = 0, q0 = 0, q1 = 0, q2 = 0, q3 = 0;
#pragma unroll
  for (int k = 0; k < 64; k += 4) {
    s0 += v[k]; q0 += v[k] * v[k];
    s1 += v[k + 1]; q1 += v[k + 1] * v[k + 1];
    s2 += v[k + 2]; q2 += v[k + 2] * v[k + 2];
    s3 += v[k + 3]; q3 += v[k + 3] * v[k + 3];
  }
  const float sum = (s0 + s1) + (s2 + s3);
  const float ssum = (q0 + q1) + (q2 + q3);
  const float mu = sum * (1.0f / 64.0f);
  const float var = ssum * (1.0f / 64.0f) - mu * mu;
  const float rstd = rsqrtf(var + 1e-5f);

  unsigned short* dst = ((t == 0) ? Qo : Ko) + ((size_t)(b * NH + h) * SEQ + n) * DH;
#pragma unroll
  for (int k8 = 0; k8 < 8; ++k8) {
    float4 gm4 = reinterpret_cast<const float4*>(gmp)[k8 * 2];
    float4 gm4b = reinterpret_cast<const float4*>(gmp)[k8 * 2 + 1];
    float4 bt4 = reinterpret_cast<const float4*>(btp)[k8 * 2];
    float4 bt4b = reinterpret_cast<const float4*>(btp)[k8 * 2 + 1];
    union { unsigned short us[8]; uint4 vv; } u;
#pragma unroll
    for (int e = 0; e < 4; ++e) {
      u.us[e] = f2bf(((v[k8 * 8 + e] - mu) * rstd * (&gm4.x)[e] + (&bt4.x)[e]) * sc);
      u.us[4 + e] = f2bf(((v[k8 * 8 + 4 + e] - mu) * rstd * (&gm4b.x)[e] + (&bt4b.x)[e]) * sc);
    }
    *reinterpret_cast<uint4*>(&dst[k8 * 8]) = u.vv;
  }
#undef CIDX
#undef ALS
#undef BLS
}

// ---------------- Flash attention: R12 barrier structure + T15 2-tile pipe overlap ----------------
// 4 waves x 32 q, swapped QK^T, no-max softmax, VALU row-sum. THREE LDS buffers; per tile
// ONE __syncthreads (vmcnt(0) drain covered by a full body -> same-head blocks stay in
// lockstep -> L2 stays hot; R15 proved counted-vmcnt breaks this). In each barrier region,
// QK^T(t+1) (matrix pipe) overlaps exp/pack(t) (VALU/trans) and PV(t). Two named S-sets
// (sa/sb), loop manually unrolled x2 so all register indices are static.
__global__ __launch_bounds__(256, 3) void attn_fwd(
    const unsigned short* __restrict__ Qb, const unsigned short* __restrict__ Kb,
    const unsigned short* __restrict__ Vtb, unsigned short* __restrict__ Ob) {
  __shared__ unsigned short kl[3][64 * 64];   // 24KB, [key][d], 128B rows, XOR-swizzled
  __shared__ unsigned short vt[3][64 * 64];   // 24KB, [d][key]
  __shared__ float linv[4][32];
  const int tid = threadIdx.x, wave = tid >> 6, lane = tid & 63;
  const int q32 = lane & 31, hi = lane >> 5;

  const int wg = blockIdx.x;
  const int lin = (wg & 7) * 96 + (wg >> 3);   // 768 = 8 * 96, bijective
  const int bh = lin >> 4;
  const int qbase = (lin & 15) * 128 + wave * 32;

  const unsigned short* qrow = Qb + ((size_t)bh * SEQ + qbase + q32) * DH + hi * 8;
  bf16x8 qf[4];
#pragma unroll
  for (int dc = 0; dc < 4; ++dc) qf[dc] = *(const bf16x8*)&qrow[dc * 16];

  const unsigned short* Kh = Kb + (size_t)bh * SEQ * DH;
  const unsigned short* Vth = Vtb + (size_t)bh * DH * SEQ;

  const int sr = tid >> 3;
  const int sc = 8 * ((tid & 7) ^ (sr & 7));
  const int ksw = (q32 & 7) << 3;

#define ASTAGE(buf, kb0)                                                      \
  do {                                                                        \
    gl2lds16(&Kh[(size_t)((kb0) + sr) * DH + sc], &kl[buf][tid * 8]);         \
    gl2lds16(&Kh[(size_t)((kb0) + sr + 32) * DH + sc], &kl[buf][tid * 8 + 2048]); \
    gl2lds16(&Vth[(size_t)sr * SEQ + (kb0) + sc], &vt[buf][tid * 8]);         \
    gl2lds16(&Vth[(size_t)(sr + 32) * SEQ + (kb0) + sc], &vt[buf][tid * 8 + 2048]); \
  } while (0)

// QK^T for tile in kl[bufc] -> (S0, S1)
#define QKCOMP(bufc, S0, S1)                                                  \
  do {                                                                        \
    S0 = (f32x16){};                                                          \
    S1 = (f32x16){};                                                          \
    __builtin_amdgcn_s_setprio(1);                                            \
    _Pragma("unroll")                                                         \
    for (int dc = 0; dc < 4; ++dc) {                                          \
      const int colb = dc * 16 + hi * 8;                                      \
      bf16x8 kf0 = *(const bf16x8*)&kl[bufc][q32 * 64 + (colb ^ ksw)];        \
      bf16x8 kf1 = *(const bf16x8*)&kl[bufc][(32 + q32) * 64 + (colb ^ ksw)]; \
      S0 = MFMA32(kf0, qf[dc], S0);                                           \
      S1 = MFMA32(kf1, qf[dc], S1);                                           \
    }                                                                         \
    __builtin_amdgcn_s_setprio(0);                                            \
  } while (0)

// exp/pack of (S0,S1) + PV from vt[bufv]; accumulates o0/o1/su*
#define SOFTPV(S0, S1, bufv)                                                  \
  do {                                                                        \
    _Pragma("unroll")                                                         \
    for (int r = 0; r < 16; r += 4) {                                         \
      S0[r + 0] = fexp2(S0[r + 0]); su0 += S0[r + 0];                         \
      S0[r + 1] = fexp2(S0[r + 1]); su1 += S0[r + 1];                         \
      S0[r + 2] = fexp2(S0[r + 2]); su2 += S0[r + 2];                         \
      S0[r + 3] = fexp2(S0[r + 3]); su3 += S0[r + 3];                         \
    }                                                                         \
    _Pragma("unroll")                                                         \
    for (int r = 0; r < 16; r += 4) {                                         \
      S1[r + 0] = fexp2(S1[r + 0]); su0 += S1[r + 0];                         \
      S1[r + 1] = fexp2(S1[r + 1]); su1 += S1[r + 1];                         \
      S1[r + 2] = fexp2(S1[r + 2]); su2 += S1[r + 2];                         \
      S1[r + 3] = fexp2(S1[r + 3]); su3 += S1[r + 3];                         \
    }                                                                         \
    bf16x8 pav[4];                                                            \
    _Pragma("unroll")                                                         \
    for (int c = 0; c < 4; ++c) {                                             \
      const int b = 8 * (c & 1);                                              \
      unsigned int wA0, wA1, wB0, wB1;                                        \
      if (c < 2) {                                                            \
        PACKBF(wA0, S0[b + 0], S0[b + 1]); PACKBF(wA1, S0[b + 2], S0[b + 3]); \
        PACKBF(wB0, S0[b + 4], S0[b + 5]); PACKBF(wB1, S0[b + 6], S0[b + 7]); \
      } else {                                                                \
        PACKBF(wA0, S1[b + 0], S1[b + 1]); PACKBF(wA1, S1[b + 2], S1[b + 3]); \
        PACKBF(wB0, S1[b + 4], S1[b + 5]); PACKBF(wB1, S1[b + 6], S1[b + 7]); \
      }                                                                       \
      SWAP32(wA0, wB0);                                                       \
      SWAP32(wA1, wB1);                                                       \
      union { unsigned int w[4]; bf16x8 v; } u;                               \
      u.w[0] = wA0; u.w[1] = wA1; u.w[2] = wB0; u.w[3] = wB1;                 \
      pav[c] = u.v;                                                           \
    }                                                                         \
    __builtin_amdgcn_s_setprio(1);                                            \
    _Pragma("unroll")                                                         \
    for (int c = 0; c < 4; ++c) {                                             \
      const int colb = c * 16 + hi * 8;                                       \
      bf16x8 vf0 = *(const bf16x8*)&vt[bufv][q32 * 64 + (colb ^ ksw)];        \
      bf16x8 vf1 = *(const bf16x8*)&vt[bufv][(32 + q32) * 64 + (colb ^ ksw)]; \
      o0 = MFMA32(pav[c], vf0, o0);                                           \
      o1 = MFMA32(pav[c], vf1, o1);                                           \
    }                                                                         \
    __builtin_amdgcn_s_setprio(0);                                            \
  } while (0)

  f32x16 o0 = {}, o1 = {};
  f32x16 sa0, sa1, sb0, sb1;
  float su0 = 0.0f, su1 = 0.0f, su2 = 0.0f, su3 = 0.0f;

  const int NT = SEQ / 64;  // 32 (even)
  // prologue: tiles 0,1 staged; S(0) computed
  ASTAGE(0, 0);
  ASTAGE(1, 64);
  __syncthreads();
  QKCOMP(0, sa0, sa1);

  // invariant at top of pass (t even): S(t) in sa; tiles t,t+1 ready; buffer (t+2)%3 free
  for (int t = 0; t + 2 < NT; t += 2) {
    ASTAGE((t + 2) % 3, (t + 2) * 64);       // overwrites buffer of tile t-1 (reads done)
    QKCOMP((t + 1) % 3, sb0, sb1);           // S(t+1); overlaps exp/pack(t) below
    SOFTPV(sa0, sa1, t % 3);                 // tile t: exp/pack + PV
    __syncthreads();                         // tile t+2 ready; all reads of t%3 done
    if (t + 3 < NT) ASTAGE((t + 3) % 3, (t + 3) * 64);
    QKCOMP((t + 2) % 3, sa0, sa1);           // S(t+2)
    SOFTPV(sb0, sb1, (t + 1) % 3);           // tile t+1
    __syncthreads();
  }
  // tail: t = NT-2 (S(NT-2) in sa; tiles NT-2, NT-1 ready)
  QKCOMP((NT - 1) % 3, sb0, sb1);            // S(NT-1)
  SOFTPV(sa0, sa1, (NT - 2) % 3);            // tile NT-2
  SOFTPV(sb0, sb1, (NT - 1) % 3);            // tile NT-1
#undef ASTAGE
#undef QKCOMP
#undef SOFTPV

  float lsum = (su0 + su1) + (su2 + su3);
  lsum += __shfl_xor(lsum, 32, 64);
  linv[wave][q32] = __builtin_amdgcn_rcpf(lsum);
  __syncthreads();

  const int b = bh / NH, h = bh % NH;
#pragma unroll
  for (int r = 0; r < 16; ++r) {
    const int qq = (r & 3) + 8 * (r >> 2) + 4 * hi;
    const float iv = linv[wave][qq];
    size_t base = ((size_t)(b * SEQ + qbase + qq)) * CD + h * DH;
    Ob[base + q32] = f2bf(o0[r] * iv);
    Ob[base + 32 + q32] = f2bf(o1[r] * iv);
  }
}

// ---------------- Proj GEMM: 128x128 tile, BK=64, swizzled LDS, fp32 out (R13) ----------------
__global__ __launch_bounds__(256) void proj_gemm(
    const unsigned short* __restrict__ Ab, const unsigned short* __restrict__ Wb,
    const float* __restrict__ bias, float* __restrict__ out) {
  __shared__ unsigned short Als[2][128 * 64];   // 32KB
  __shared__ unsigned short Bls[2][128 * 64];   // 32KB
  const int tid = threadIdx.x;
  const int wid = tid >> 6, lane = tid & 63;
  const int g = lane >> 4, cl = lane & 15;
  const int bm = blockIdx.x, bn = blockIdx.y;
  const int wr = (wid >> 1) * 64, wc = (wid & 1) * 64;

  f32x4 acc[4][4] = {};

  const int srow = tid >> 3;                      // 0..31
  const int scol = ((tid & 7) ^ (srow & 7)) * 8;
  const unsigned short* Abase = Ab + (size_t)(bm * 128 + srow) * CD + scol;
  const unsigned short* Bbase = Wb + (size_t)(bn * 128 + srow) * CD + scol;

#define PSTG(buf, kt)                                                         \
  do {                                                                        \
    gl2lds16(Abase + (size_t)0 * 32 * CD + (kt) * 64, &Als[buf][0 * 2048 + tid * 8]); \
    gl2lds16(Abase + (size_t)1 * 32 * CD + (kt) * 64, &Als[buf][1 * 2048 + tid * 8]); \
    gl2lds16(Abase + (size_t)2 * 32 * CD + (kt) * 64, &Als[buf][2 * 2048 + tid * 8]); \
    gl2lds16(Abase + (size_t)3 * 32 * CD + (kt) * 64, &Als[buf][3 * 2048 + tid * 8]); \
    gl2lds16(Bbase + (size_t)0 * 32 * CD + (kt) * 64, &Bls[buf][0 * 2048 + tid * 8]); \
    gl2lds16(Bbase + (size_t)1 * 32 * CD + (kt) * 64, &Bls[buf][1 * 2048 + tid * 8]); \
    gl2lds16(Bbase + (size_t)2 * 32 * CD + (kt) * 64, &Bls[buf][2 * 2048 + tid * 8]); \
    gl2lds16(Bbase + (size_t)3 * 32 * CD + (kt) * 64, &Bls[buf][3 * 2048 + tid * 8]); \
  } while (0)

  PSTG(0, 0);
  __syncthreads();
  const int NKT = CD / 64;  // 12
  for (int kt = 0; kt < NKT; ++kt) {
    const int cur = kt & 1;
    if (kt + 1 < NKT) PSTG(cur ^ 1, kt + 1);
    bf16x8 bfr[4][2];
#pragma unroll
    for (int j = 0; j < 4; ++j) {
      const int Bcol = wc + j * 16 + cl;
      const int sw = (Bcol & 7) << 3;
      bfr[j][0] = *(const bf16x8*)&Bls[cur][Bcol * 64 + ((g * 8) ^ sw)];
      bfr[j][1] = *(const bf16x8*)&Bls[cur][Bcol * 64 + ((32 + g * 8) ^ sw)];
    }
    __builtin_amdgcn_s_setprio(1);
#pragma unroll
    for (int i = 0; i < 4; ++i) {
      const int Arow = wr + i * 16 + cl;
      const int sw = (Arow & 7) << 3;
      bf16x8 a0 = *(const bf16x8*)&Als[cur][Arow * 64 + ((g * 8) ^ sw)];
      bf16x8 a1 = *(const bf16x8*)&Als[cur][Arow * 64 + ((32 + g * 8) ^ sw)];
#pragma unroll
      for (int j = 0; j < 4; ++j) {
        acc[i][j] = MFMA(a0, bfr[j][0], acc[i][j]);
        acc[i][j] = MFMA(a1, bfr[j][1], acc[i][j]);
      }
    }
    __builtin_amdgcn_s_setprio(0);
    __syncthreads();
  }
#undef PSTG

  const int j0 = bn * 128 + wc;
  float pb4[4];
#pragma unroll
  for (int j = 0; j < 4; ++j) pb4[j] = bias[j0 + j * 16 + cl];
#pragma unroll
  for (int i = 0; i < 4; ++i) {
#pragma unroll
    for (int r = 0; r < 4; ++r) {
      const int m = bm * 128 + wr + i * 16 + g * 4 + r;
      float* orow = out + (size_t)m * CD + j0;
#pragma unroll
      for (int j = 0; j < 4; ++j) orow[j * 16 + cl] = acc[i][j][r] + pb4[j];
    }
  }
}

extern "C" void kernel_launch(void* const* d_in, const int* in_sizes, int n_in,
                              void* d_out, int out_size, void* d_ws, size_t ws_size,
                              hipStream_t stream) {
  const float* x = (const float*)d_in[0];
  const float* qkv_w = (const float*)d_in[1];
  const float* qkv_b = (const float*)d_in[2];
  const float* proj_w = (const float*)d_in[3];
  const float* proj_b = (const float*)d_in[4];
  const float* q_gamma = (const float*)d_in[5];
  const float* q_beta = (const float*)d_in[6];
  const float* k_gamma = (const float*)d_in[7];
  const float* k_beta = (const float*)d_in[8];
  float* out = (float*)d_out;

  char* w = (char*)d_ws;
  unsigned short* Xb = (unsigned short*)w; w += (size_t)MROWS * CD * 2;
  unsigned short* Wq = (unsigned short*)w; w += (size_t)NQKV * CD * 2;
  unsigned short* Wp = (unsigned short*)w; w += (size_t)CD * CD * 2;
  unsigned short* Qo = (unsigned short*)w; w += (size_t)BB * NH * SEQ * DH * 2;
  unsigned short* Ko = (unsigned short*)w; w += (size_t)BB * NH * SEQ * DH * 2;
  unsigned short* Vt = (unsigned short*)w; w += (size_t)BB * NH * SEQ * DH * 2;  // [b,h,d,n]
  unsigned short* Ob = (unsigned short*)w; w += (size_t)MROWS * CD * 2;

  cvt_all<<<(CN3 + 255) / 256, 256, 0, stream>>>(x, qkv_w, proj_w, Xb, Wq, Wp);

  qkv_gemm<<<(MROWS / 128) * (NQKV / 128), 256, 0, stream>>>(
      Xb, Wq, qkv_b, q_gamma, q_beta, k_gamma, k_beta, Qo, Ko, Vt);

  attn_fwd<<<SEQ / 128 * BB * NH, 256, 0, stream>>>(Qo, Ko, Vt, Ob);

  proj_gemm<<<dim3(MROWS / 128, CD / 128), 256, 0, stream>>>(Ob, Wp, proj_b, out);
}

// Round 17
// 133.852 us; speedup vs baseline: 1.5296x; 1.5296x over previous
//
#include <hip/hip_runtime.h>
#include <hip/hip_bf16.h>
#include <cstdint>
#include <cstddef>

#define BB 4
#define SEQ 2048
#define CD 768
#define NH 12
#define DH 64
#define MROWS (BB*SEQ)      // 8192
#define NQKV (3*CD)         // 2304

typedef float f32x4 __attribute__((ext_vector_type(4)));
typedef float f32x16 __attribute__((ext_vector_type(16)));
typedef short bf16x8 __attribute__((ext_vector_type(8)));

static __device__ __forceinline__ unsigned short f2bf(float f) {
  union { float f; unsigned int u; } cv; cv.f = f;
  unsigned int u = cv.u;
  unsigned int r = (u + 0x7FFFu + ((u >> 16) & 1u)) >> 16;
  return (unsigned short)r;
}

// raw v_exp_f32: our exponents are bounded (|x| <= ~23), no OCML fixups needed
static __device__ __forceinline__ float fexp2(float x) {
#if __has_builtin(__builtin_amdgcn_exp2f)
  return __builtin_amdgcn_exp2f(x);
#else
  float r; asm("v_exp_f32 %0, %1" : "=v"(r) : "v"(x)); return r;
#endif
}

#define GAS __attribute__((address_space(1)))
#define LAS __attribute__((address_space(3)))
static __device__ __forceinline__ void gl2lds16(const void* g, void* l) {
  __builtin_amdgcn_global_load_lds((const GAS void*)g, (LAS void*)l, 16, 0, 0);
}

#define MFMA(a, b, c) __builtin_amdgcn_mfma_f32_16x16x32_bf16((a), (b), (c), 0, 0, 0)
#define MFMA32(a, b, c) __builtin_amdgcn_mfma_f32_32x32x16_bf16((a), (b), (c), 0, 0, 0)
#define PACKBF(dst, x, y) asm("v_cvt_pk_bf16_f32 %0, %1, %2" : "=v"(dst) : "v"(x), "v"(y))
#define SWAP32(a, b) asm("v_permlane32_swap_b32 %0, %1" : "+v"(a), "+v"(b))

// 0.125 (1/sqrt(Dh)) * log2(e): folded into Q's gamma/beta so softmax uses exp2 directly.
// With LN'd q,k scores are bounded (|log2 score| <= 11.5) -> no max subtraction needed.
#define QSC 0.18033688011112042f

// ---------------- fp32 -> bf16 convert (x, qkv_w, proj_w in one launch) ----------------
#define CN1 (MROWS * CD / 4)
#define CN2 (CN1 + NQKV * CD / 4)
#define CN3 (CN2 + CD * CD / 4)
__global__ __launch_bounds__(256) void cvt_all(
    const float* __restrict__ x, const float* __restrict__ wq, const float* __restrict__ wp,
    unsigned short* __restrict__ Xb, unsigned short* __restrict__ Wq,
    unsigned short* __restrict__ Wp) {
  int i = blockIdx.x * 256 + threadIdx.x;
  if (i >= CN3) return;
  const float* src;
  unsigned short* dst;
  int k;
  if (i < CN1) { src = x; dst = Xb; k = i; }
  else if (i < CN2) { src = wq; dst = Wq; k = i - CN1; }
  else { src = wp; dst = Wp; k = i - CN2; }
  float4 v = reinterpret_cast<const float4*>(src)[k];
  unsigned int lo = (unsigned int)f2bf(v.x) | ((unsigned int)f2bf(v.y) << 16);
  unsigned int hi = (unsigned int)f2bf(v.z) | ((unsigned int)f2bf(v.w) << 16);
  reinterpret_cast<uint2*>(dst)[k] = make_uint2(lo, hi);
}

// ---------------- QKV GEMM: 128x128 tile, BK=64, 4 waves, swizzled LDS ----------------
// Epilogue: acc -> LDS (f32, slot-XOR swizzled) -> per-thread full-row LN (no shuffles)
// -> fully coalesced 16B stores. t==0 -> LN -> Qo[b,h,n,d]; t==1 -> LN -> Ko; t==2 -> Vt[b,h,d,n].
__global__ __launch_bounds__(256) void qkv_gemm(
    const unsigned short* __restrict__ Xb, const unsigned short* __restrict__ Wb,
    const float* __restrict__ bias,
    const float* __restrict__ qg, const float* __restrict__ qbt,
    const float* __restrict__ kg, const float* __restrict__ kbt,
    unsigned short* __restrict__ Qo, unsigned short* __restrict__ Ko,
    unsigned short* __restrict__ Vt) {
  __shared__ unsigned short smem[4 * 128 * 64];   // 64KB: staging dbuf, then f32 C-buffer
#define ALS(buf) (&smem[(buf) * 8192])
#define BLS(buf) (&smem[16384 + (buf) * 8192])
  const int tid = threadIdx.x;
  const int wid = tid >> 6, lane = tid & 63;
  const int g = lane >> 4, cl = lane & 15;
  const int wr = (wid >> 1) * 64, wc = (wid & 1) * 64;

  const int wg = blockIdx.x;
  const int wgid = (wg & 7) * 144 + (wg >> 3);
  const int bm = wgid / 18, bn = wgid % 18;

  f32x4 acc[4][4] = {};

  const int srow = tid >> 3;                      // 0..31
  const int scol = ((tid & 7) ^ (srow & 7)) * 8;  // pre-swizzled source col
  const unsigned short* Abase = Xb + (size_t)(bm * 128 + srow) * CD + scol;
  const unsigned short* Bbase = Wb + (size_t)(bn * 128 + srow) * CD + scol;

#define QSTG(buf, kt)                                                         \
  do {                                                                        \
    gl2lds16(Abase + (size_t)0 * 32 * CD + (kt) * 64, ALS(buf) + 0 * 2048 + tid * 8); \
    gl2lds16(Abase + (size_t)1 * 32 * CD + (kt) * 64, ALS(buf) + 1 * 2048 + tid * 8); \
    gl2lds16(Abase + (size_t)2 * 32 * CD + (kt) * 64, ALS(buf) + 2 * 2048 + tid * 8); \
    gl2lds16(Abase + (size_t)3 * 32 * CD + (kt) * 64, ALS(buf) + 3 * 2048 + tid * 8); \
    gl2lds16(Bbase + (size_t)0 * 32 * CD + (kt) * 64, BLS(buf) + 0 * 2048 + tid * 8); \
    gl2lds16(Bbase + (size_t)1 * 32 * CD + (kt) * 64, BLS(buf) + 1 * 2048 + tid * 8); \
    gl2lds16(Bbase + (size_t)2 * 32 * CD + (kt) * 64, BLS(buf) + 2 * 2048 + tid * 8); \
    gl2lds16(Bbase + (size_t)3 * 32 * CD + (kt) * 64, BLS(buf) + 3 * 2048 + tid * 8); \
  } while (0)

  QSTG(0, 0);
  __syncthreads();
  const int NKT = CD / 64;  // 12
  for (int kt = 0; kt < NKT; ++kt) {
    const int cur = kt & 1;
    if (kt + 1 < NKT) QSTG(cur ^ 1, kt + 1);
    bf16x8 bfr[4][2];
#pragma unroll
    for (int j = 0; j < 4; ++j) {
      const int Bcol = wc + j * 16 + cl;
      const int sw = (Bcol & 7) << 3;
      bfr[j][0] = *(const bf16x8*)&BLS(cur)[Bcol * 64 + ((g * 8) ^ sw)];
      bfr[j][1] = *(const bf16x8*)&BLS(cur)[Bcol * 64 + ((32 + g * 8) ^ sw)];
    }
    __builtin_amdgcn_s_setprio(1);
#pragma unroll
    for (int i = 0; i < 4; ++i) {
      const int Arow = wr + i * 16 + cl;
      const int sw = (Arow & 7) << 3;
      bf16x8 a0 = *(const bf16x8*)&ALS(cur)[Arow * 64 + ((g * 8) ^ sw)];
      bf16x8 a1 = *(const bf16x8*)&ALS(cur)[Arow * 64 + ((32 + g * 8) ^ sw)];
#pragma unroll
      for (int j = 0; j < 4; ++j) {
        acc[i][j] = MFMA(a0, bfr[j][0], acc[i][j]);
        acc[i][j] = MFMA(a1, bfr[j][1], acc[i][j]);
      }
    }
    __builtin_amdgcn_s_setprio(0);
    __syncthreads();
  }
#undef QSTG

  // ---- LDS-bounce epilogue ----
  float* cb = (float*)smem;
#define CIDX(r, c) ((r) * 128 + (((((c) >> 2)) ^ ((r) & 31)) << 2) + ((c) & 3))
#pragma unroll
  for (int i = 0; i < 4; ++i)
#pragma unroll
    for (int j = 0; j < 4; ++j)
#pragma unroll
      for (int r = 0; r < 4; ++r)
        cb[CIDX(wr + i * 16 + g * 4 + r, wc + j * 16 + cl)] = acc[i][j][r];
  __syncthreads();

  const int t = bn / 6;
  const int h0 = (bn % 6) * 2;
  const int j0 = bn * 128;

  if (t == 2) {
    const int col = tid >> 1, nh = tid & 1;
    const int h = h0 + (col >> 6), d = col & 63;
    const float bia = bias[j0 + col];
    const int m0 = bm * 128;
    const int b = m0 >> 11;
    const int nn0 = (m0 & 2047) + nh * 64;
    unsigned short* dst = &Vt[((size_t)(b * NH + h) * DH + d) * SEQ + nn0];
#pragma unroll
    for (int k8 = 0; k8 < 8; ++k8) {
      union { unsigned short us[8]; uint4 v; } u;
#pragma unroll
      for (int e = 0; e < 8; ++e)
        u.us[e] = f2bf(cb[CIDX(nh * 64 + k8 * 8 + e, col)] + bia);
      *reinterpret_cast<uint4*>(&dst[k8 * 8]) = u.v;
    }
    return;
  }

  const int nl = tid >> 1, half = tid & 1;
  const int h = h0 + half;
  const int m = bm * 128 + nl;
  const int b = m >> 11, n = m & 2047;
  const float* gmp = (t == 0) ? qg : kg;
  const float* btp = (t == 0) ? qbt : kbt;
  const float sc = (t == 0) ? QSC : 1.0f;
  const float* bi = bias + j0 + half * 64;

  float v[64];
#pragma unroll
  for (int k4 = 0; k4 < 16; ++k4) {
    f32x4 q = *(const f32x4*)&cb[nl * 128 + ((((half * 16 + k4)) ^ (nl & 31)) << 2)];
    float4 b4 = reinterpret_cast<const float4*>(bi)[k4];
    v[k4 * 4 + 0] = q[0] + b4.x;
    v[k4 * 4 + 1] = q[1] + b4.y;
    v[k4 * 4 + 2] = q[2] + b4.z;
    v[k4 * 4 + 3] = q[3] + b4.w;
  }
  float s0 = 0, s1 = 0, s2 = 0, s3 = 0, q0 = 0, q1 = 0, q2 = 0, q3 = 0;
#pragma unroll
  for (int k = 0; k < 64; k += 4) {
    s0 += v[k]; q0 += v[k] * v[k];
    s1 += v[k + 1]; q1 += v[k + 1] * v[k + 1];
    s2 += v[k + 2]; q2 += v[k + 2] * v[k + 2];
    s3 += v[k + 3]; q3 += v[k + 3] * v[k + 3];
  }
  const float sum = (s0 + s1) + (s2 + s3);
  const float ssum = (q0 + q1) + (q2 + q3);
  const float mu = sum * (1.0f / 64.0f);
  const float var = ssum * (1.0f / 64.0f) - mu * mu;
  const float rstd = rsqrtf(var + 1e-5f);

  unsigned short* dst = ((t == 0) ? Qo : Ko) + ((size_t)(b * NH + h) * SEQ + n) * DH;
#pragma unroll
  for (int k8 = 0; k8 < 8; ++k8) {
    float4 gm4 = reinterpret_cast<const float4*>(gmp)[k8 * 2];
    float4 gm4b = reinterpret_cast<const float4*>(gmp)[k8 * 2 + 1];
    float4 bt4 = reinterpret_cast<const float4*>(btp)[k8 * 2];
    float4 bt4b = reinterpret_cast<const float4*>(btp)[k8 * 2 + 1];
    union { unsigned short us[8]; uint4 vv; } u;
#pragma unroll
    for (int e = 0; e < 4; ++e) {
      u.us[e] = f2bf(((v[k8 * 8 + e] - mu) * rstd * (&gm4.x)[e] + (&bt4.x)[e]) * sc);
      u.us[4 + e] = f2bf(((v[k8 * 8 + 4 + e] - mu) * rstd * (&gm4b.x)[e] + (&bt4b.x)[e]) * sc);
    }
    *reinterpret_cast<uint4*>(&dst[k8 * 8]) = u.vv;
  }
#undef CIDX
#undef ALS
#undef BLS
}

// ---------------- Flash attention: R8 structure, VALU row-sum (no ones-MFMA) ----------------
__global__ __launch_bounds__(256, 3) void attn_fwd(
    const unsigned short* __restrict__ Qb, const unsigned short* __restrict__ Kb,
    const unsigned short* __restrict__ Vtb, unsigned short* __restrict__ Ob) {
  __shared__ unsigned short kl[2][64 * 64];   // [key][d], 128B rows, XOR-swizzled
  __shared__ unsigned short vt[2][64 * 64];   // [d][key], 128B rows, XOR-swizzled
  __shared__ float linv[4][32];
  const int tid = threadIdx.x, wave = tid >> 6, lane = tid & 63;
  const int q32 = lane & 31, hi = lane >> 5;

  const int wg = blockIdx.x;
  const int lin = (wg & 7) * 96 + (wg >> 3);   // 768 = 8 * 96, bijective
  const int bh = lin >> 4;
  const int qbase = (lin & 15) * 128 + wave * 32;

  const unsigned short* qrow = Qb + ((size_t)bh * SEQ + qbase + q32) * DH + hi * 8;
  bf16x8 qf[4];
#pragma unroll
  for (int dc = 0; dc < 4; ++dc) qf[dc] = *(const bf16x8*)&qrow[dc * 16];

  const unsigned short* Kh = Kb + (size_t)bh * SEQ * DH;
  const unsigned short* Vth = Vtb + (size_t)bh * DH * SEQ;

  const int sr = tid >> 3;
  const int sc = 8 * ((tid & 7) ^ (sr & 7));
  const int ksw = (q32 & 7) << 3;

#define ASTAGE(buf, kb0)                                                      \
  do {                                                                        \
    gl2lds16(&Kh[(size_t)((kb0) + sr) * DH + sc], &kl[buf][tid * 8]);         \
    gl2lds16(&Kh[(size_t)((kb0) + sr + 32) * DH + sc], &kl[buf][tid * 8 + 2048]); \
    gl2lds16(&Vth[(size_t)sr * SEQ + (kb0) + sc], &vt[buf][tid * 8]);         \
    gl2lds16(&Vth[(size_t)(sr + 32) * SEQ + (kb0) + sc], &vt[buf][tid * 8 + 2048]); \
  } while (0)

  f32x16 o0 = {}, o1 = {};
  float su0 = 0.0f, su1 = 0.0f, su2 = 0.0f, su3 = 0.0f;

  ASTAGE(0, 0);
  __syncthreads();
  const int NT = SEQ / 64;  // 32
#pragma unroll 2
  for (int it = 0; it < NT; ++it) {
    const int cur = it & 1;
    if (it + 1 < NT) ASTAGE(cur ^ 1, (it + 1) * 64);

    f32x16 s0 = {}, s1 = {};
    __builtin_amdgcn_s_setprio(1);
#pragma unroll
    for (int dc = 0; dc < 4; ++dc) {
      const int colb = dc * 16 + hi * 8;
      bf16x8 kf0 = *(const bf16x8*)&kl[cur][q32 * 64 + (colb ^ ksw)];
      bf16x8 kf1 = *(const bf16x8*)&kl[cur][(32 + q32) * 64 + (colb ^ ksw)];
      s0 = MFMA32(kf0, qf[dc], s0);
      s1 = MFMA32(kf1, qf[dc], s1);
    }
    __builtin_amdgcn_s_setprio(0);

#pragma unroll
    for (int r = 0; r < 16; r += 4) {
      s0[r + 0] = fexp2(s0[r + 0]); su0 += s0[r + 0];
      s0[r + 1] = fexp2(s0[r + 1]); su1 += s0[r + 1];
      s0[r + 2] = fexp2(s0[r + 2]); su2 += s0[r + 2];
      s0[r + 3] = fexp2(s0[r + 3]); su3 += s0[r + 3];
    }
#pragma unroll
    for (int r = 0; r < 16; r += 4) {
      s1[r + 0] = fexp2(s1[r + 0]); su0 += s1[r + 0];
      s1[r + 1] = fexp2(s1[r + 1]); su1 += s1[r + 1];
      s1[r + 2] = fexp2(s1[r + 2]); su2 += s1[r + 2];
      s1[r + 3] = fexp2(s1[r + 3]); su3 += s1[r + 3];
    }

    bf16x8 pav[4];
#pragma unroll
    for (int c = 0; c < 4; ++c) {
      const int b = 8 * (c & 1);
      unsigned int wA0, wA1, wB0, wB1;
      if (c < 2) {
        PACKBF(wA0, s0[b + 0], s0[b + 1]); PACKBF(wA1, s0[b + 2], s0[b + 3]);
        PACKBF(wB0, s0[b + 4], s0[b + 5]); PACKBF(wB1, s0[b + 6], s0[b + 7]);
      } else {
        PACKBF(wA0, s1[b + 0], s1[b + 1]); PACKBF(wA1, s1[b + 2], s1[b + 3]);
        PACKBF(wB0, s1[b + 4], s1[b + 5]); PACKBF(wB1, s1[b + 6], s1[b + 7]);
      }
      SWAP32(wA0, wB0);
      SWAP32(wA1, wB1);
      union { unsigned int w[4]; bf16x8 v; } u;
      u.w[0] = wA0; u.w[1] = wA1; u.w[2] = wB0; u.w[3] = wB1;
      pav[c] = u.v;
    }

    __builtin_amdgcn_s_setprio(1);
#pragma unroll
    for (int c = 0; c < 4; ++c) {
      const int colb = c * 16 + hi * 8;
      bf16x8 vf0 = *(const bf16x8*)&vt[cur][q32 * 64 + (colb ^ ksw)];
      bf16x8 vf1 = *(const bf16x8*)&vt[cur][(32 + q32) * 64 + (colb ^ ksw)];
      o0 = MFMA32(pav[c], vf0, o0);
      o1 = MFMA32(pav[c], vf1, o1);
    }
    __builtin_amdgcn_s_setprio(0);
    __syncthreads();
  }
#undef ASTAGE

  float lsum = (su0 + su1) + (su2 + su3);
  lsum += __shfl_xor(lsum, 32, 64);
  linv[wave][q32] = __builtin_amdgcn_rcpf(lsum);
  __syncthreads();

  const int b = bh / NH, h = bh % NH;
#pragma unroll
  for (int r = 0; r < 16; ++r) {
    const int qq = (r & 3) + 8 * (r >> 2) + 4 * hi;
    const float iv = linv[wave][qq];
    size_t base = ((size_t)(b * SEQ + qbase + qq)) * CD + h * DH;
    Ob[base + q32] = f2bf(o0[r] * iv);
    Ob[base + 32 + q32] = f2bf(o1[r] * iv);
  }
}

// ---------------- Proj GEMM: 128x128 tile, BK=64, swizzled LDS, fp32 out ----------------
__global__ __launch_bounds__(256) void proj_gemm(
    const unsigned short* __restrict__ Ab, const unsigned short* __restrict__ Wb,
    const float* __restrict__ bias, float* __restrict__ out) {
  __shared__ unsigned short Als[2][128 * 64];   // 32KB
  __shared__ unsigned short Bls[2][128 * 64];   // 32KB
  const int tid = threadIdx.x;
  const int wid = tid >> 6, lane = tid & 63;
  const int g = lane >> 4, cl = lane & 15;
  const int bm = blockIdx.x, bn = blockIdx.y;
  const int wr = (wid >> 1) * 64, wc = (wid & 1) * 64;

  f32x4 acc[4][4] = {};

  const int srow = tid >> 3;                      // 0..31
  const int scol = ((tid & 7) ^ (srow & 7)) * 8;
  const unsigned short* Abase = Ab + (size_t)(bm * 128 + srow) * CD + scol;
  const unsigned short* Bbase = Wb + (size_t)(bn * 128 + srow) * CD + scol;

#define PSTG(buf, kt)                                                         \
  do {                                                                        \
    gl2lds16(Abase + (size_t)0 * 32 * CD + (kt) * 64, &Als[buf][0 * 2048 + tid * 8]); \
    gl2lds16(Abase + (size_t)1 * 32 * CD + (kt) * 64, &Als[buf][1 * 2048 + tid * 8]); \
    gl2lds16(Abase + (size_t)2 * 32 * CD + (kt) * 64, &Als[buf][2 * 2048 + tid * 8]); \
    gl2lds16(Abase + (size_t)3 * 32 * CD + (kt) * 64, &Als[buf][3 * 2048 + tid * 8]); \
    gl2lds16(Bbase + (size_t)0 * 32 * CD + (kt) * 64, &Bls[buf][0 * 2048 + tid * 8]); \
    gl2lds16(Bbase + (size_t)1 * 32 * CD + (kt) * 64, &Bls[buf][1 * 2048 + tid * 8]); \
    gl2lds16(Bbase + (size_t)2 * 32 * CD + (kt) * 64, &Bls[buf][2 * 2048 + tid * 8]); \
    gl2lds16(Bbase + (size_t)3 * 32 * CD + (kt) * 64, &Bls[buf][3 * 2048 + tid * 8]); \
  } while (0)

  PSTG(0, 0);
  __syncthreads();
  const int NKT = CD / 64;  // 12
  for (int kt = 0; kt < NKT; ++kt) {
    const int cur = kt & 1;
    if (kt + 1 < NKT) PSTG(cur ^ 1, kt + 1);
    bf16x8 bfr[4][2];
#pragma unroll
    for (int j = 0; j < 4; ++j) {
      const int Bcol = wc + j * 16 + cl;
      const int sw = (Bcol & 7) << 3;
      bfr[j][0] = *(const bf16x8*)&Bls[cur][Bcol * 64 + ((g * 8) ^ sw)];
      bfr[j][1] = *(const bf16x8*)&Bls[cur][Bcol * 64 + ((32 + g * 8) ^ sw)];
    }
    __builtin_amdgcn_s_setprio(1);
#pragma unroll
    for (int i = 0; i < 4; ++i) {
      const int Arow = wr + i * 16 + cl;
      const int sw = (Arow & 7) << 3;
      bf16x8 a0 = *(const bf16x8*)&Als[cur][Arow * 64 + ((g * 8) ^ sw)];
      bf16x8 a1 = *(const bf16x8*)&Als[cur][Arow * 64 + ((32 + g * 8) ^ sw)];
#pragma unroll
      for (int j = 0; j < 4; ++j) {
        acc[i][j] = MFMA(a0, bfr[j][0], acc[i][j]);
        acc[i][j] = MFMA(a1, bfr[j][1], acc[i][j]);
      }
    }
    __builtin_amdgcn_s_setprio(0);
    __syncthreads();
  }
#undef PSTG

  const int j0 = bn * 128 + wc;
  float pb4[4];
#pragma unroll
  for (int j = 0; j < 4; ++j) pb4[j] = bias[j0 + j * 16 + cl];
#pragma unroll
  for (int i = 0; i < 4; ++i) {
#pragma unroll
    for (int r = 0; r < 4; ++r) {
      const int m = bm * 128 + wr + i * 16 + g * 4 + r;
      float* orow = out + (size_t)m * CD + j0;
#pragma unroll
      for (int j = 0; j < 4; ++j) orow[j * 16 + cl] = acc[i][j][r] + pb4[j];
    }
  }
}

extern "C" void kernel_launch(void* const* d_in, const int* in_sizes, int n_in,
                              void* d_out, int out_size, void* d_ws, size_t ws_size,
                              hipStream_t stream) {
  const float* x = (const float*)d_in[0];
  const float* qkv_w = (const float*)d_in[1];
  const float* qkv_b = (const float*)d_in[2];
  const float* proj_w = (const float*)d_in[3];
  const float* proj_b = (const float*)d_in[4];
  const float* q_gamma = (const float*)d_in[5];
  const float* q_beta = (const float*)d_in[6];
  const float* k_gamma = (const float*)d_in[7];
  const float* k_beta = (const float*)d_in[8];
  float* out = (float*)d_out;

  char* w = (char*)d_ws;
  unsigned short* Xb = (unsigned short*)w; w += (size_t)MROWS * CD * 2;
  unsigned short* Wq = (unsigned short*)w; w += (size_t)NQKV * CD * 2;
  unsigned short* Wp = (unsigned short*)w; w += (size_t)CD * CD * 2;
  unsigned short* Qo = (unsigned short*)w; w += (size_t)BB * NH * SEQ * DH * 2;
  unsigned short* Ko = (unsigned short*)w; w += (size_t)BB * NH * SEQ * DH * 2;
  unsigned short* Vt = (unsigned short*)w; w += (size_t)BB * NH * SEQ * DH * 2;  // [b,h,d,n]
  unsigned short* Ob = (unsigned short*)w; w += (size_t)MROWS * CD * 2;

  cvt_all<<<(CN3 + 255) / 256, 256, 0, stream>>>(x, qkv_w, proj_w, Xb, Wq, Wp);

  qkv_gemm<<<(MROWS / 128) * (NQKV / 128), 256, 0, stream>>>(
      Xb, Wq, qkv_b, q_gamma, q_beta, k_gamma, k_beta, Qo, Ko, Vt);

  attn_fwd<<<SEQ / 128 * BB * NH, 256, 0, stream>>>(Qo, Ko, Vt, Ob);

  proj_gemm<<<dim3(MROWS / 128, CD / 128), 256, 0, stream>>>(Ob, Wp, proj_b, out);
}